// Round 1
// 483.338 us; speedup vs baseline: 1.1867x; 1.1867x over previous
//
#include <hip/hip_runtime.h>
#include <cstdint>

// out[M,N] = A[M,K] (fp32) x W[N,K] (int8 stored as int32 by harness — verified R1/R2) * scale[N]
// M=8192 N=4096 K=4096
#define M_DIM 8192
#define N_DIM 4096
#define K_DIM 4096

typedef unsigned short u16;
typedef unsigned int u32;
typedef __attribute__((ext_vector_type(8))) short short8;     // 8 x bf16 (4 VGPRs)
typedef __attribute__((ext_vector_type(4))) float floatx4;    // MFMA accumulator

#define AS1 __attribute__((address_space(1)))
#define AS3 __attribute__((address_space(3)))

static __device__ __forceinline__ u16 f2bf(float f) {
    // round-to-nearest-even fp32 -> bf16 (inputs are finite normals)
    u32 x = __float_as_uint(f);
    x += 0x7FFFu + ((x >> 16) & 1u);
    return (u16)(x >> 16);
}

// ---------------- prepass: A fp32 -> bf16 ----------------
__global__ void cvt_a_kernel(const float4* __restrict__ in, ushort4* __restrict__ out, int n4) {
    int i = blockIdx.x * blockDim.x + threadIdx.x;
    int stride = gridDim.x * blockDim.x;
    for (; i < n4; i += stride) {
        float4 f = in[i];
        ushort4 u;
        u.x = f2bf(f.x); u.y = f2bf(f.y); u.z = f2bf(f.z); u.w = f2bf(f.w);
        out[i] = u;
    }
}

// ---------------- prepass: W int32 elements -> bf16 (int8 values are exact in bf16) ------------
__global__ void cvt_w_kernel(const int4* __restrict__ in, ushort4* __restrict__ out, int n4) {
    int i = blockIdx.x * blockDim.x + threadIdx.x;
    int stride = gridDim.x * blockDim.x;
    for (; i < n4; i += stride) {
        int4 w = in[i];
        ushort4 u;
        u.x = f2bf((float)w.x);
        u.y = f2bf((float)w.y);
        u.z = f2bf((float)w.z);
        u.w = f2bf((float)w.w);
        out[i] = u;
    }
}

// ================= main GEMM: 256x256 tile, BK=64, 8-wave, 8-phase counted-vmcnt =================
// Port of the verified 256^2 8-phase template (learn_hip m194-m201): double-buffered 128 KiB LDS,
// raw s_barrier (no vmcnt(0) drain), one vmcnt(8) per K-tile, setprio(1) around each MFMA cluster.
//
// LDS: [A0|B0|A1|B1], each 256 rows x 64 bf16 (128 B row = 8 x 16B chunks). Swizzle: LDS position
// p of row r holds global chunk p ^ (r&7) — applied via pre-swizzled per-lane GLOBAL source
// (global_load_lds dst stays lane-linear) and folded into ds_read addresses. Both the staging
// write pattern and the fragment read pattern (lanes 0..15 = rows r, chunks (ks*4+q)^(r&7))
// distribute uniformly over all 32 banks -> conflict-free.
//
// Schedule per K-tile t (buffer bt = t&1), quadrants of each wave's 128x64 output:
//   ph0: read aF<-M0(8) bF0<-N0(4)            | MFMA Q0 = acc[0..3][0..1]
//   ph1: read bF1<-N1(4)                      | MFMA Q1 = acc[0..3][2..3]   (B halves released)
//   ph2: read aF<-M1(8); stage (t+2).B0,B1    | MFMA Q2 = acc[4..7][0..1]   (A halves released)
//   ph3: stage (t+2).A0,A1; vmcnt(8)          | MFMA Q3 = acc[4..7][2..3]
// vmcnt(8) leaves exactly tile t+2's 8 loads in flight; tile t+1 (staged 4+ phases earlier) is
// guaranteed landed before any wave reads it at ph0 of t+1 (vmcnt precedes ph3's mid-barrier).

#define GLL(s, d) __builtin_amdgcn_global_load_lds((const AS1 u32*)(const void*)(s), \
                                                   (AS3 u32*)(void*)(d), 16, 0, 0)

#define STAGE_A(kt, h, d) do { \
    const u16* s_ = aSrcTh + (size_t)(h) * (128 * K_DIM) + (size_t)(kt) * 64; \
    char* d_ = ldsC + (d) * 65536 + (h) * 16384 + waveOff; \
    GLL(s_, d_); \
    GLL(s_ + 64 * K_DIM, d_ + 8192); \
} while (0)

#define STAGE_B(kt, h, d) do { \
    const u16* s_ = bSrcTh + (size_t)(h) * (128 * K_DIM) + (size_t)(kt) * 64; \
    char* d_ = ldsC + 32768 + (d) * 65536 + (h) * 16384 + waveOff; \
    GLL(s_, d_); \
    GLL(s_ + 64 * K_DIM, d_ + 8192); \
} while (0)

#define RD(off) (*(const short8*)&lds[(off)])
#define MMA(d, a, b) (d) = __builtin_amdgcn_mfma_f32_16x16x32_bf16((a), (b), (d), 0, 0, 0)
#define BAR() __builtin_amdgcn_s_barrier()
#define FENCE() asm volatile("" ::: "memory")            // blocks load hoist across raw s_barrier
#define WAIT_LGKM0() asm volatile("s_waitcnt lgkmcnt(0)" ::: "memory")

#define PH0(bt) do { \
    _Pragma("unroll") for (int mt_ = 0; mt_ < 4; ++mt_) { \
      aF[mt_][0] = RD((bt) * 32768 + aRowOff + mt_ * 1024 + c0); \
      aF[mt_][1] = RD((bt) * 32768 + aRowOff + mt_ * 1024 + c1); \
    } \
    _Pragma("unroll") for (int nt_ = 0; nt_ < 2; ++nt_) { \
      bF0[nt_][0] = RD((bt) * 32768 + 16384 + bRowOff + nt_ * 1024 + c0); \
      bF0[nt_][1] = RD((bt) * 32768 + 16384 + bRowOff + nt_ * 1024 + c1); \
    } \
    BAR(); WAIT_LGKM0(); \
    __builtin_amdgcn_s_setprio(1); \
    _Pragma("unroll") for (int mt_ = 0; mt_ < 4; ++mt_) \
      _Pragma("unroll") for (int nt_ = 0; nt_ < 2; ++nt_) { \
        MMA(acc[mt_][nt_], aF[mt_][0], bF0[nt_][0]); \
        MMA(acc[mt_][nt_], aF[mt_][1], bF0[nt_][1]); \
      } \
    __builtin_amdgcn_s_setprio(0); \
    BAR(); FENCE(); \
} while (0)

#define PH1(bt) do { \
    _Pragma("unroll") for (int nt_ = 0; nt_ < 2; ++nt_) { \
      bF1[nt_][0] = RD((bt) * 32768 + 16384 + bRowOff + (2 + nt_) * 1024 + c0); \
      bF1[nt_][1] = RD((bt) * 32768 + 16384 + bRowOff + (2 + nt_) * 1024 + c1); \
    } \
    BAR(); WAIT_LGKM0(); \
    __builtin_amdgcn_s_setprio(1); \
    _Pragma("unroll") for (int mt_ = 0; mt_ < 4; ++mt_) \
      _Pragma("unroll") for (int nt_ = 0; nt_ < 2; ++nt_) { \
        MMA(acc[mt_][2 + nt_], aF[mt_][0], bF1[nt_][0]); \
        MMA(acc[mt_][2 + nt_], aF[mt_][1], bF1[nt_][1]); \
      } \
    __builtin_amdgcn_s_setprio(0); \
    BAR(); FENCE(); \
} while (0)

#define PH2(t, bt, doStg) do { \
    _Pragma("unroll") for (int mt_ = 0; mt_ < 4; ++mt_) { \
      aF[mt_][0] = RD((bt) * 32768 + aRowOff + (4 + mt_) * 1024 + c0); \
      aF[mt_][1] = RD((bt) * 32768 + aRowOff + (4 + mt_) * 1024 + c1); \
    } \
    if (doStg) { STAGE_B((t) + 2, 0, (bt)); STAGE_B((t) + 2, 1, (bt)); } \
    BAR(); WAIT_LGKM0(); \
    __builtin_amdgcn_s_setprio(1); \
    _Pragma("unroll") for (int mt_ = 0; mt_ < 4; ++mt_) \
      _Pragma("unroll") for (int nt_ = 0; nt_ < 2; ++nt_) { \
        MMA(acc[4 + mt_][nt_], aF[mt_][0], bF0[nt_][0]); \
        MMA(acc[4 + mt_][nt_], aF[mt_][1], bF0[nt_][1]); \
      } \
    __builtin_amdgcn_s_setprio(0); \
    BAR(); FENCE(); \
} while (0)

#define PH3(t, bt, doStg, VM) do { \
    if (doStg) { STAGE_A((t) + 2, 0, (bt)); STAGE_A((t) + 2, 1, (bt)); } \
    asm volatile("s_waitcnt vmcnt(" #VM ")" ::: "memory"); \
    BAR(); WAIT_LGKM0(); \
    __builtin_amdgcn_s_setprio(1); \
    _Pragma("unroll") for (int mt_ = 0; mt_ < 4; ++mt_) \
      _Pragma("unroll") for (int nt_ = 0; nt_ < 2; ++nt_) { \
        MMA(acc[4 + mt_][2 + nt_], aF[mt_][0], bF1[nt_][0]); \
        MMA(acc[4 + mt_][2 + nt_], aF[mt_][1], bF1[nt_][1]); \
      } \
    __builtin_amdgcn_s_setprio(0); \
    BAR(); FENCE(); \
} while (0)

__global__ void __launch_bounds__(512, 2)
gemm_bf16_256(const u16* __restrict__ A, const u16* __restrict__ W,
              const float* __restrict__ scaler, float* __restrict__ out) {
    __shared__ u16 lds[65536];   // 128 KiB: [A0|B0|A1|B1], each 256x64 bf16

    const int tid  = threadIdx.x;
    const int wave = tid >> 6;
    const int lane = tid & 63;
    const int r = lane & 15;       // MFMA row/col within 16
    const int q = lane >> 4;       // quad 0..3
    const int waveM = wave >> 2;   // 0..1 -> 128-row half of A tile
    const int waveN = wave & 3;    // 0..3 -> 64-col slice of B tile

    const int mBase = blockIdx.y * 256;
    const int nBase = blockIdx.x * 256;

    const int aRowOff = (waveM * 128 + r) * 64;   // u16 elements
    const int bRowOff = (waveN * 64 + r) * 64;
    const int c0 = (q ^ (r & 7)) * 8;             // swizzled chunk, ks=0
    const int c1 = c0 ^ 32;                       // ks=1 (chunk ^ 4)
    const int waveOff = wave * 1024;              // gload_lds dst: wave base + lane*16
    char* ldsC = (char*)lds;

    // staging: thread covers row tid>>3 (of a 64-row issue), dst chunk tid&7; global source
    // chunk is XOR-swizzled so LDS stays lane-linear (rule #21: inverse-swz source + swz read).
    const int srow = tid >> 3;
    const int schk = (tid & 7) ^ (srow & 7);
    const u16* aSrcTh = A + (size_t)(mBase + srow) * K_DIM + schk * 8;
    const u16* bSrcTh = W + (size_t)(nBase + srow) * K_DIM + schk * 8;

    short8 aF[4][2], bF0[2][2], bF1[2][2];   // 64 VGPR of fragments
    floatx4 acc[8][4] = {};                  // 128 VGPR accumulator

    // prologue: stage tiles 0 and 1 completely; leave tile 1's 8 loads in flight
    STAGE_B(0, 0, 0); STAGE_B(0, 1, 0); STAGE_A(0, 0, 0); STAGE_A(0, 1, 0);
    STAGE_B(1, 0, 1); STAGE_B(1, 1, 1); STAGE_A(1, 0, 1); STAGE_A(1, 1, 1);
    asm volatile("s_waitcnt vmcnt(8)" ::: "memory");
    BAR(); FENCE();

    #pragma unroll 1
    for (int tt = 0; tt < 31; ++tt) {        // tiles 0..61, 2 per iteration
        const int t0 = 2 * tt;
        PH0(0); PH1(0); PH2(t0, 0, 1); PH3(t0, 0, 1, 8);
        PH0(1); PH1(1); PH2(t0 + 1, 1, 1); PH3(t0 + 1, 1, 1, 8);
    }
    // tile 62 (buf 0): no more staging; vmcnt(0) drains tile 63's loads
    PH0(0); PH1(0); PH2(62, 0, 0); PH3(62, 0, 0, 0);
    // tile 63 (buf 1)
    PH0(1); PH1(1); PH2(63, 1, 0); PH3(63, 1, 0, 0);

    // epilogue: C/D layout col(n)=lane&15, row(m)=q*4+reg; fuse per-channel scale
    const int mW = mBase + waveM * 128;
    const int nW = nBase + waveN * 64;
    #pragma unroll
    for (int nt = 0; nt < 4; ++nt) {
        const int n = nW + nt * 16 + r;
        const float s = scaler[n];
        #pragma unroll
        for (int mt = 0; mt < 8; ++mt) {
            const int m0 = mW + mt * 16 + q * 4;
            #pragma unroll
            for (int j = 0; j < 4; ++j)
                out[(size_t)(m0 + j) * N_DIM + n] = acc[mt][nt][j] * s;
        }
    }
}

// ---------------- fallback (ws too small): fp32 vector GEMM, W as int32 ----------------
__global__ void __launch_bounds__(256)
gemm_fallback_kernel(const float* __restrict__ A, const int* __restrict__ W,
                     const float* __restrict__ scaler, float* __restrict__ out) {
    __shared__ float As[64][33];
    __shared__ float Ws[64][33];
    const int tx = threadIdx.x & 15, ty = threadIdx.x >> 4;
    const int mBase = blockIdx.y * 64, nBase = blockIdx.x * 64;
    float acc[4][4] = {};
    for (int kt = 0; kt < K_DIM; kt += 32) {
        for (int i = threadIdx.x; i < 64 * 32; i += 256) {
            int rr = i >> 5, cc = i & 31;
            As[rr][cc] = A[(size_t)(mBase + rr) * K_DIM + kt + cc];
            Ws[rr][cc] = (float)W[(size_t)(nBase + rr) * K_DIM + kt + cc];
        }
        __syncthreads();
        for (int kk = 0; kk < 32; ++kk) {
            float av[4], bv[4];
#pragma unroll
            for (int i = 0; i < 4; ++i) av[i] = As[ty * 4 + i][kk];
#pragma unroll
            for (int j = 0; j < 4; ++j) bv[j] = Ws[tx * 4 + j][kk];
#pragma unroll
            for (int i = 0; i < 4; ++i)
#pragma unroll
                for (int j = 0; j < 4; ++j) acc[i][j] += av[i] * bv[j];
        }
        __syncthreads();
    }
#pragma unroll
    for (int i = 0; i < 4; ++i)
#pragma unroll
        for (int j = 0; j < 4; ++j) {
            int m = mBase + ty * 4 + i, n = nBase + tx * 4 + j;
            out[(size_t)m * N_DIM + n] = acc[i][j] * scaler[n];
        }
}

extern "C" void kernel_launch(void* const* d_in, const int* in_sizes, int n_in,
                              void* d_out, int out_size, void* d_ws, size_t ws_size,
                              hipStream_t stream) {
    const float* A      = (const float*)d_in[0];
    const int*   W32    = (const int*)d_in[1];   // int8 values materialized as int32 (verified R1/R2)
    const float* scaler = (const float*)d_in[2];
    float* out          = (float*)d_out;

    const size_t needA = (size_t)M_DIM * K_DIM * sizeof(u16);  // 64 MiB
    const size_t needW = (size_t)N_DIM * K_DIM * sizeof(u16);  // 32 MiB

    if (ws_size >= needA + needW) {
        u16* Abf = (u16*)d_ws;
        u16* Wbf = (u16*)((char*)d_ws + needA);
        cvt_a_kernel<<<4096, 256, 0, stream>>>((const float4*)A, (ushort4*)Abf, M_DIM * K_DIM / 4);
        cvt_w_kernel<<<2048, 256, 0, stream>>>((const int4*)W32, (ushort4*)Wbf, N_DIM * K_DIM / 4);
        dim3 grid(N_DIM / 256, M_DIM / 256);  // 16 x 32 = 512 blocks, 1/CU, 2 clean rounds
        gemm_bf16_256<<<grid, 512, 0, stream>>>(Abf, Wbf, scaler, out);
    } else {
        dim3 grid(N_DIM / 64, M_DIM / 64);
        gemm_fallback_kernel<<<grid, 256, 0, stream>>>(A, W32, scaler, out);
    }
}